// Round 1
// baseline (1560.914 us; speedup 1.0000x reference)
//
#include <hip/hip_runtime.h>
#include <math.h>

// Problem constants (from reference)
constexpr int M    = 4096;   // BATCH
constexpr int K1   = 1024;   // INPUT_DIM
constexpr int R    = 2048;   // RESERVOIR_DIM
constexpr int MAXR = 4096;   // MAX_RESERVOIR_DIM

// Tiling
constexpr int BM = 128;
constexpr int BN = 64;
constexpr int BK = 16;
constexpr int TM = 8;        // per-thread rows
constexpr int TN = 4;        // per-thread cols

// Fused: input_part + reservoir_part + 3 gate GEMMs + epilogue + pad-zeroing.
// fp32 VALU (no fp32 MFMA on CDNA4). Correctness-first baseline.
__global__ __launch_bounds__(256, 2)
void slnn_fused_kernel(const float* __restrict__ X,     // [4096][1024]
                       const float* __restrict__ S,     // [4096][4096] (state)
                       const float* __restrict__ Wres,  // [4096][4096]
                       const float* __restrict__ Win,   // [4096][1024]
                       const float* __restrict__ Wg,    // [12288][1024]
                       float* __restrict__ out)         // [4096][4096]
{
    __shared__ float As[BK][BM];        // transposed A tile: As[k][m]
    __shared__ float Bs[4][BK][BN];     // transposed B tiles: Bs[g][k][n]

    const int tid  = threadIdx.x;
    const int row0 = blockIdx.x * BM;
    const int col0 = blockIdx.y * BN;

    const int tr = tid >> 4;            // 0..15
    const int tc = tid & 15;            // 0..15
    const int m0 = tr * TM;             // 0..120
    const int n0 = tc * TN;             // 0..60

    float acc_in[TM][TN] = {};
    float acc_i [TM][TN] = {};
    float acc_f [TM][TN] = {};
    float acc_o [TM][TN] = {};
    float acc_r [TM][TN] = {};

    // ---------------- Phase A: K = K1, A = x, B = {Win, Wg_i, Wg_f, Wg_o} (row-major NxK) ----
    {
        const float* Bsrc0 = Win + (size_t)col0 * K1;
        const float* Bsrc1 = Wg  + (size_t)(col0        ) * K1;
        const float* Bsrc2 = Wg  + (size_t)(col0 +     R) * K1;
        const float* Bsrc3 = Wg  + (size_t)(col0 + 2 * R) * K1;
        const float* Bsrc[4] = {Bsrc0, Bsrc1, Bsrc2, Bsrc3};

        const int am  = tid >> 2;       // 0..63 (A-row slot; +64 for second)
        const int akq = tid & 3;        // k-quad

        for (int k0 = 0; k0 < K1; k0 += BK) {
            // stage A (transposed): 2 float4 per thread
            #pragma unroll
            for (int i = 0; i < 2; ++i) {
                const int m = am + i * 64;
                float4 v = *(const float4*)(X + (size_t)(row0 + m) * K1 + k0 + akq * 4);
                As[akq * 4 + 0][m] = v.x;
                As[akq * 4 + 1][m] = v.y;
                As[akq * 4 + 2][m] = v.z;
                As[akq * 4 + 3][m] = v.w;
            }
            // stage the 4 B tiles (transposed): 1 float4 per thread per matrix
            #pragma unroll
            for (int g = 0; g < 4; ++g) {
                float4 v = *(const float4*)(Bsrc[g] + (size_t)am * K1 + k0 + akq * 4);
                Bs[g][akq * 4 + 0][am] = v.x;
                Bs[g][akq * 4 + 1][am] = v.y;
                Bs[g][akq * 4 + 2][am] = v.z;
                Bs[g][akq * 4 + 3][am] = v.w;
            }
            __syncthreads();
            #pragma unroll
            for (int k = 0; k < BK; ++k) {
                float a[TM];
                *(float4*)&a[0] = *(const float4*)&As[k][m0];
                *(float4*)&a[4] = *(const float4*)&As[k][m0 + 4];
                float4 b0 = *(const float4*)&Bs[0][k][n0];
                float4 b1 = *(const float4*)&Bs[1][k][n0];
                float4 b2 = *(const float4*)&Bs[2][k][n0];
                float4 b3 = *(const float4*)&Bs[3][k][n0];
                const float bb0[4] = {b0.x, b0.y, b0.z, b0.w};
                const float bb1[4] = {b1.x, b1.y, b1.z, b1.w};
                const float bb2[4] = {b2.x, b2.y, b2.z, b2.w};
                const float bb3[4] = {b3.x, b3.y, b3.z, b3.w};
                #pragma unroll
                for (int u = 0; u < TM; ++u) {
                    #pragma unroll
                    for (int v = 0; v < TN; ++v) {
                        acc_in[u][v] = fmaf(a[u], bb0[v], acc_in[u][v]);
                        acc_i [u][v] = fmaf(a[u], bb1[v], acc_i [u][v]);
                        acc_f [u][v] = fmaf(a[u], bb2[v], acc_f [u][v]);
                        acc_o [u][v] = fmaf(a[u], bb3[v], acc_o [u][v]);
                    }
                }
            }
            __syncthreads();
        }
    }

    // ---------------- Phase B: K = R, A = prev_state (stride MAXR), B = Wres (K x N, stride MAXR)
    {
        const int am  = tid >> 2;       // 0..63
        const int akq = tid & 3;
        const int kk  = tid >> 4;       // 0..15
        const int nq  = tid & 15;       // 0..15

        for (int k0 = 0; k0 < R; k0 += BK) {
            #pragma unroll
            for (int i = 0; i < 2; ++i) {
                const int m = am + i * 64;
                float4 v = *(const float4*)(S + (size_t)(row0 + m) * MAXR + k0 + akq * 4);
                As[akq * 4 + 0][m] = v.x;
                As[akq * 4 + 1][m] = v.y;
                As[akq * 4 + 2][m] = v.z;
                As[akq * 4 + 3][m] = v.w;
            }
            {
                float4 v = *(const float4*)(Wres + (size_t)(k0 + kk) * MAXR + col0 + nq * 4);
                *(float4*)&Bs[0][kk][nq * 4] = v;
            }
            __syncthreads();
            #pragma unroll
            for (int k = 0; k < BK; ++k) {
                float a[TM];
                *(float4*)&a[0] = *(const float4*)&As[k][m0];
                *(float4*)&a[4] = *(const float4*)&As[k][m0 + 4];
                float4 b = *(const float4*)&Bs[0][k][n0];
                const float bb[4] = {b.x, b.y, b.z, b.w};
                #pragma unroll
                for (int u = 0; u < TM; ++u) {
                    #pragma unroll
                    for (int v = 0; v < TN; ++v) {
                        acc_r[u][v] = fmaf(a[u], bb[v], acc_r[u][v]);
                    }
                }
            }
            __syncthreads();
        }
    }

    // ---------------- Epilogue ----------------
    #pragma unroll
    for (int u = 0; u < TM; ++u) {
        const int m = row0 + m0 + u;
        float4 pv = *(const float4*)(S + (size_t)m * MAXR + col0 + n0);
        const float p[4] = {pv.x, pv.y, pv.z, pv.w};
        float r[4];
        #pragma unroll
        for (int v = 0; v < TN; ++v) {
            const float ig = 1.0f / (1.0f + expf(-acc_i[u][v]));
            const float fg = 1.0f / (1.0f + expf(-acc_f[u][v]));
            const float og = 1.0f / (1.0f + expf(-acc_o[u][v]));
            float s = 0.9f * (fg * p[v])
                    + 0.1f * tanhf(ig * (acc_in[u][v] + acc_r[u][v]));
            s *= og;
            if (s > 0.5f) s -= 0.5f;
            r[v] = s;
        }
        float4 ov = make_float4(r[0], r[1], r[2], r[3]);
        *(float4*)(out + (size_t)m * MAXR + col0 + n0) = ov;
        // zero the padded half [R, MAXR) for this tile's columns
        float4 z = make_float4(0.f, 0.f, 0.f, 0.f);
        *(float4*)(out + (size_t)m * MAXR + R + col0 + n0) = z;
    }
}

extern "C" void kernel_launch(void* const* d_in, const int* in_sizes, int n_in,
                              void* d_out, int out_size, void* d_ws, size_t ws_size,
                              hipStream_t stream) {
    const float* X    = (const float*)d_in[0];  // inputs            (4096,1,1024)
    const float* S    = (const float*)d_in[1];  // state             (4096,1,4096)
    const float* Wres = (const float*)d_in[2];  // reservoir_weights (4096,4096)
    const float* Win  = (const float*)d_in[3];  // input_weights     (4096,1024)
    const float* Wg   = (const float*)d_in[4];  // gate_weights      (12288,1024)
    float* out = (float*)d_out;

    dim3 grid(M / BM, R / BN);   // 32 x 32 = 1024 blocks
    slnn_fused_kernel<<<grid, dim3(256), 0, stream>>>(X, S, Wres, Win, Wg, out);
}

// Round 5
// 684.393 us; speedup vs baseline: 2.2807x; 2.2807x over previous
//
#include <hip/hip_runtime.h>
#include <math.h>

// Problem constants
constexpr int M    = 4096;   // BATCH
constexpr int K1   = 1024;   // INPUT_DIM
constexpr int R    = 2048;   // RESERVOIR_DIM
constexpr int MAXR = 4096;   // MAX_RESERVOIR_DIM

// Tiling: block = 128x32 output tile, 4 waves, each wave 32x32.
constexpr int BM = 128;
constexpr int BN = 32;
constexpr int BK = 32;
constexpr int BKP = BK + 8;  // padded LDS row (80B stride -> worst 2-way bank alias, free per m136)

typedef _Float16 f16x8 __attribute__((ext_vector_type(8)));
typedef _Float16 f16x4 __attribute__((ext_vector_type(4)));
typedef float    f32x4 __attribute__((ext_vector_type(4)));

// Split fp32 -> fp16 hi + fp16 lo*1024 (lo scaled into fp16 normal range).
// a ~= hi + lo/1024, residual ~ 2^-22 * |a|.
__device__ __forceinline__ void split4(const float4 v, f16x4* hi, f16x4* lo) {
    float a[4] = {v.x, v.y, v.z, v.w};
    f16x4 h, l;
#pragma unroll
    for (int j = 0; j < 4; ++j) {
        _Float16 hh = (_Float16)a[j];
        h[j] = hh;
        l[j] = (_Float16)((a[j] - (float)hh) * 1024.0f);
    }
    *hi = h; *lo = l;
}

// Fused: [input_part | i | f | o gates] GEMM (K=1024) + reservoir GEMM (K=2048)
// via fp16x3 split MFMA, + sigmoid/tanh/leak/spike epilogue + pad zeroing.
__global__ __launch_bounds__(256, 2)
void slnn_mfma_kernel(const float* __restrict__ X,     // [4096][1024]
                      const float* __restrict__ S,     // [4096][4096]
                      const float* __restrict__ Wres,  // [4096][4096] (use [k][n], k,n<2048)
                      const float* __restrict__ Win,   // [4096][1024] (rows 0..2047 used, NxK)
                      const float* __restrict__ Wg,    // [12288][1024] (rows 0..6143 used, NxK)
                      float* __restrict__ out)         // [4096][4096]
{
    __shared__ _Float16 Ah[BM][BKP];
    __shared__ _Float16 Al[BM][BKP];
    __shared__ _Float16 Bh[4][BN][BKP];
    __shared__ _Float16 Bl[4][BN][BKP];

    const int tid  = threadIdx.x;
    const int w    = tid >> 6;        // wave 0..3
    const int lane = tid & 63;
    const int row0 = blockIdx.x * BM;
    const int col0 = blockIdx.y * BN;

    const int lrow = lane & 15;       // fragment row/col within 16
    const int koff = (lane >> 4) * 8; // fragment k offset (8 halfs)

    // staging indices
    const int s_r  = tid >> 3;        // 0..31 (A: +32*i; B: n)
    const int s_kq = tid & 7;         // k-quad (4 floats)

    // [gemm: 0=in,1=i,2=f,3=o][mfrag][nfrag]
    f32x4 hh[4][2][2] = {};
    f32x4 cx[4][2][2] = {};

    // ---------------- Phase A: A = X, B = {Win, Wg_i, Wg_f, Wg_o}, K = 1024 ----------------
    for (int k0 = 0; k0 < K1; k0 += BK) {
        // stage A: 128x32 fp32 -> split fp16 pair, [m][k] layout
#pragma unroll
        for (int i = 0; i < 4; ++i) {
            const int row = s_r + 32 * i;
            float4 v = *(const float4*)(X + (size_t)(row0 + row) * K1 + k0 + s_kq * 4);
            f16x4 h, l; split4(v, &h, &l);
            *(f16x4*)&Ah[row][s_kq * 4] = h;
            *(f16x4*)&Al[row][s_kq * 4] = l;
        }
        // stage B: 4 matrices, each 32(n) x 32(k), [n][k] layout (global is NxK row-major)
        {
            const int n = s_r;
            f16x4 h, l;
            float4 v0 = *(const float4*)(Win + (size_t)(col0 + n) * K1 + k0 + s_kq * 4);
            split4(v0, &h, &l);
            *(f16x4*)&Bh[0][n][s_kq * 4] = h;
            *(f16x4*)&Bl[0][n][s_kq * 4] = l;
#pragma unroll
            for (int g = 1; g < 4; ++g) {
                float4 v = *(const float4*)(Wg + (size_t)(col0 + n + (g - 1) * R) * K1 + k0 + s_kq * 4);
                split4(v, &h, &l);
                *(f16x4*)&Bh[g][n][s_kq * 4] = h;
                *(f16x4*)&Bl[g][n][s_kq * 4] = l;
            }
        }
        __syncthreads();

        f16x8 ah[2], al[2];
#pragma unroll
        for (int mf = 0; mf < 2; ++mf) {
            const int m = w * 32 + mf * 16 + lrow;
            ah[mf] = *(const f16x8*)&Ah[m][koff];
            al[mf] = *(const f16x8*)&Al[m][koff];
        }
#pragma unroll
        for (int g = 0; g < 4; ++g) {
#pragma unroll
            for (int nf = 0; nf < 2; ++nf) {
                const int n = nf * 16 + lrow;
                f16x8 bh = *(const f16x8*)&Bh[g][n][koff];
                f16x8 bl = *(const f16x8*)&Bl[g][n][koff];
#pragma unroll
                for (int mf = 0; mf < 2; ++mf) {
                    hh[g][mf][nf] = __builtin_amdgcn_mfma_f32_16x16x32_f16(ah[mf], bh, hh[g][mf][nf], 0, 0, 0);
                    cx[g][mf][nf] = __builtin_amdgcn_mfma_f32_16x16x32_f16(ah[mf], bl, cx[g][mf][nf], 0, 0, 0);
                    cx[g][mf][nf] = __builtin_amdgcn_mfma_f32_16x16x32_f16(al[mf], bh, cx[g][mf][nf], 0, 0, 0);
                }
            }
        }
        __syncthreads();
    }

    // fold cross terms: total = hh + cx/1024
#pragma unroll
    for (int g = 0; g < 4; ++g)
#pragma unroll
        for (int mf = 0; mf < 2; ++mf)
#pragma unroll
            for (int nf = 0; nf < 2; ++nf)
                hh[g][mf][nf] += cx[g][mf][nf] * (1.0f / 1024.0f);

    // ---------------- Phase B: A = prev_state (S, stride MAXR), B = Wres[k][n], K = 2048 ----
    f32x4 rhh[2][2] = {};
    f32x4 rcx[2][2] = {};
    const int wn  = tid & 31;         // n within tile
    const int wkb = (tid >> 5) * 4;   // k base (4 scalars along k)

    for (int k0 = 0; k0 < R; k0 += BK) {
#pragma unroll
        for (int i = 0; i < 4; ++i) {
            const int row = s_r + 32 * i;
            float4 v = *(const float4*)(S + (size_t)(row0 + row) * MAXR + k0 + s_kq * 4);
            f16x4 h, l; split4(v, &h, &l);
            *(f16x4*)&Ah[row][s_kq * 4] = h;
            *(f16x4*)&Al[row][s_kq * 4] = l;
        }
        {
            // transpose-stage Wres: 4 scalar loads along k at fixed n (coalesced across wn)
            float4 v;
            v.x = Wres[(size_t)(k0 + wkb + 0) * MAXR + col0 + wn];
            v.y = Wres[(size_t)(k0 + wkb + 1) * MAXR + col0 + wn];
            v.z = Wres[(size_t)(k0 + wkb + 2) * MAXR + col0 + wn];
            v.w = Wres[(size_t)(k0 + wkb + 3) * MAXR + col0 + wn];
            f16x4 h, l; split4(v, &h, &l);
            *(f16x4*)&Bh[0][wn][wkb] = h;
            *(f16x4*)&Bl[0][wn][wkb] = l;
        }
        __syncthreads();

        f16x8 ah[2], al[2];
#pragma unroll
        for (int mf = 0; mf < 2; ++mf) {
            const int m = w * 32 + mf * 16 + lrow;
            ah[mf] = *(const f16x8*)&Ah[m][koff];
            al[mf] = *(const f16x8*)&Al[m][koff];
        }
#pragma unroll
        for (int nf = 0; nf < 2; ++nf) {
            const int n = nf * 16 + lrow;
            f16x8 bh = *(const f16x8*)&Bh[0][n][koff];
            f16x8 bl = *(const f16x8*)&Bl[0][n][koff];
#pragma unroll
            for (int mf = 0; mf < 2; ++mf) {
                rhh[mf][nf] = __builtin_amdgcn_mfma_f32_16x16x32_f16(ah[mf], bh, rhh[mf][nf], 0, 0, 0);
                rcx[mf][nf] = __builtin_amdgcn_mfma_f32_16x16x32_f16(ah[mf], bl, rcx[mf][nf], 0, 0, 0);
                rcx[mf][nf] = __builtin_amdgcn_mfma_f32_16x16x32_f16(al[mf], bh, rcx[mf][nf], 0, 0, 0);
            }
        }
        __syncthreads();
    }
#pragma unroll
    for (int mf = 0; mf < 2; ++mf)
#pragma unroll
        for (int nf = 0; nf < 2; ++nf)
            rhh[mf][nf] += rcx[mf][nf] * (1.0f / 1024.0f);

    // ---------------- Epilogue ----------------
    // C frag layout: col = lane&15, row = (lane>>4)*4 + i  (m89-verified, dtype-independent)
#pragma unroll
    for (int mf = 0; mf < 2; ++mf) {
#pragma unroll
        for (int nf = 0; nf < 2; ++nf) {
#pragma unroll
            for (int i = 0; i < 4; ++i) {
                const int row = row0 + w * 32 + mf * 16 + (lane >> 4) * 4 + i;
                const int col = col0 + nf * 16 + (lane & 15);
                const float p   = S[(size_t)row * MAXR + col];
                const float vin = hh[0][mf][nf][i];
                const float vi  = hh[1][mf][nf][i];
                const float vf  = hh[2][mf][nf][i];
                const float vo  = hh[3][mf][nf][i];
                const float vr  = rhh[mf][nf][i];
                const float ig = 1.0f / (1.0f + expf(-vi));
                const float fg = 1.0f / (1.0f + expf(-vf));
                const float og = 1.0f / (1.0f + expf(-vo));
                float s = 0.9f * (fg * p) + 0.1f * tanhf(ig * (vin + vr));
                s *= og;
                if (s > 0.5f) s -= 0.5f;
                out[(size_t)row * MAXR + col] = s;
                out[(size_t)row * MAXR + R + col] = 0.0f;  // zero the pad half
            }
        }
    }
}

extern "C" void kernel_launch(void* const* d_in, const int* in_sizes, int n_in,
                              void* d_out, int out_size, void* d_ws, size_t ws_size,
                              hipStream_t stream) {
    const float* X    = (const float*)d_in[0];
    const float* S    = (const float*)d_in[1];
    const float* Wres = (const float*)d_in[2];
    const float* Win  = (const float*)d_in[3];
    const float* Wg   = (const float*)d_in[4];
    float* out = (float*)d_out;

    dim3 grid(M / BM, R / BN);   // 32 x 64 = 2048 blocks
    slnn_mfma_kernel<<<grid, dim3(256), 0, stream>>>(X, S, Wres, Win, Wg, out);
}

// Round 8
// 555.394 us; speedup vs baseline: 2.8105x; 1.2323x over previous
//
#include <hip/hip_runtime.h>
#include <math.h>

// Problem constants
constexpr int M    = 4096;   // BATCH
constexpr int K1   = 1024;   // INPUT_DIM
constexpr int R    = 2048;   // RESERVOIR_DIM
constexpr int MAXR = 4096;   // MAX_RESERVOIR_DIM

constexpr int BM = 128;
constexpr int BN = 32;
constexpr int BK = 32;
constexpr int BKP = BK + 8;  // fallback kernel pad

typedef _Float16 f16x8 __attribute__((ext_vector_type(8)));
typedef _Float16 f16x4 __attribute__((ext_vector_type(4)));
typedef float    f32x4 __attribute__((ext_vector_type(4)));

// ws chunk-layout byte offsets (chunk = 16B = 8 halfs = 8 consecutive k of one row)
// A-type arrays: chunk index = kchunk * NROWS + row   (kchunk = k/8)
// B-type arrays: chunk index = kchunk * NCOLS + col
constexpr size_t WS_XH = 0;                    // X hi:  128 kc * 4096 rows
constexpr size_t WS_XL = 8388608;
constexpr size_t WS_SH = 16777216;             // S hi:  256 kc * 4096 rows
constexpr size_t WS_SL = 33554432;
constexpr size_t WS_GH = 50331648;             // 4 mats (Win, Wg_i, Wg_f, Wg_o): each 128 kc * 2048
constexpr size_t WS_GL = 67108864;
constexpr size_t WS_RH = 83886080;             // Wres^T: 256 kc * 2048 cols
constexpr size_t WS_RL = 92274688;
constexpr size_t WS_NEED = 100663296;
constexpr size_t G_MAT_HALFS = 2097152;        // per-matrix stride in halfs (262144 chunks)

__device__ __forceinline__ void split4(const float4 v, f16x4* hi, f16x4* lo) {
    float a[4] = {v.x, v.y, v.z, v.w};
    f16x4 h, l;
#pragma unroll
    for (int j = 0; j < 4; ++j) {
        _Float16 hh = (_Float16)a[j];
        h[j] = hh;
        l[j] = (_Float16)((a[j] - (float)hh) * 1024.0f);
    }
    *hi = h; *lo = l;
}

__device__ __forceinline__ void glds16(const void* g, void* l) {
    __builtin_amdgcn_global_load_lds((const __attribute__((address_space(1))) void*)g,
                                     (__attribute__((address_space(3))) void*)l, 16, 0, 0);
}

// ---------------- convert kernels ----------------
// Row-major input [rows][stride]: tile 64 rows x 128 k. Output chunk idx = kc*nrows + row.
__global__ __launch_bounds__(256)
void convert_rowmajor(const float* __restrict__ in, int in_stride,
                      _Float16* __restrict__ outH, _Float16* __restrict__ outL, int nrows)
{
    __shared__ _Float16 lh[64][136];
    __shared__ _Float16 ll[64][136];
    const int t  = threadIdx.x;
    const int r0 = blockIdx.x * 64;
    const int k0 = blockIdx.y * 128;
#pragma unroll
    for (int i = 0; i < 8; ++i) {
        int idx = i * 256 + t; int kq = idx & 31; int r = idx >> 5;
        float4 v = *(const float4*)(in + (size_t)(r0 + r) * in_stride + k0 + kq * 4);
        f16x4 h, l; split4(v, &h, &l);
        *(f16x4*)&lh[r][kq * 4] = h;
        *(f16x4*)&ll[r][kq * 4] = l;
    }
    __syncthreads();
#pragma unroll
    for (int i = 0; i < 4; ++i) {
        int idx = i * 256 + t; int r = idx & 63; int c = idx >> 6;
        size_t o = ((size_t)(k0 >> 3) + c) * nrows + r0 + r;
        *((f16x8*)outH + o) = *(const f16x8*)&lh[r][c * 8];
        *((f16x8*)outL + o) = *(const f16x8*)&ll[r][c * 8];
    }
}

// Transposed input (Wres [k][n]): tile 128 k x 64 n. Output chunk idx = kc*ncols + n,
// chunk data = in[kc*8+j][n] (j=0..7).
__global__ __launch_bounds__(256)
void convert_colmajor(const float* __restrict__ in, int in_stride,
                      _Float16* __restrict__ outH, _Float16* __restrict__ outL, int ncols)
{
    __shared__ _Float16 lh[64][136];   // [n][k]
    __shared__ _Float16 ll[64][136];
    const int t  = threadIdx.x;
    const int k0 = blockIdx.x * 128;
    const int n0 = blockIdx.y * 64;
#pragma unroll
    for (int i = 0; i < 8; ++i) {
        int idx = i * 256 + t; int n4 = idx & 15; int k = idx >> 4;
        float4 v = *(const float4*)(in + (size_t)(k0 + k) * in_stride + n0 + n4 * 4);
        float a[4] = {v.x, v.y, v.z, v.w};
#pragma unroll
        for (int j = 0; j < 4; ++j) {
            _Float16 h = (_Float16)a[j];
            lh[n4 * 4 + j][k] = h;
            ll[n4 * 4 + j][k] = (_Float16)((a[j] - (float)h) * 1024.0f);
        }
    }
    __syncthreads();
#pragma unroll
    for (int i = 0; i < 4; ++i) {
        int idx = i * 256 + t; int r = idx & 63; int c = idx >> 6;
        size_t o = ((size_t)(k0 >> 3) + c) * ncols + n0 + r;
        *((f16x8*)outH + o) = *(const f16x8*)&lh[r][c * 8];
        *((f16x8*)outL + o) = *(const f16x8*)&ll[r][c * 8];
    }
}

// ---------------- main fused GEMM (preconverted, global_load_lds) ----------------
// LDS chunk layouts (conflict-free, deposit-linear):
//   A: chunk = slot*128 + m_local   (slot = k16-subchunk 0..3)
//   B: chunk = g*128 + slot*32 + n_local
__global__ __launch_bounds__(256, 2)
void slnn_mfma_pre(const _Float16* __restrict__ XH, const _Float16* __restrict__ XL,
                   const _Float16* __restrict__ SH, const _Float16* __restrict__ SL,
                   const _Float16* __restrict__ GH, const _Float16* __restrict__ GL,
                   const _Float16* __restrict__ RH, const _Float16* __restrict__ RL,
                   const float* __restrict__ S, float* __restrict__ out)
{
    __shared__ _Float16 AH[4096];   // 512 chunks
    __shared__ _Float16 AL[4096];
    __shared__ _Float16 BH[4096];
    __shared__ _Float16 BL[4096];

    const int tid  = threadIdx.x;
    const int w    = tid >> 6;
    const int lane = tid & 63;
    const int row0 = blockIdx.x * BM;
    const int col0 = blockIdx.y * BN;

    const int lr = lane & 15;
    const int sl = lane >> 4;

    f32x4 hh[4][2][2] = {};
    f32x4 cx[4][2][2] = {};

    // ---------------- Phase A: K=1024 (32 k-steps) ----------------
    for (int kt = 0; kt < 32; ++kt) {
#pragma unroll
        for (int p = 0; p < 2; ++p) {
            size_t ga = ((size_t)(kt * 4 + w)) * 4096 + row0 + p * 64 + lane;
            glds16(XH + ga * 8, &AH[(w * 128 + p * 64) * 8]);
            glds16(XL + ga * 8, &AL[(w * 128 + p * 64) * 8]);
            int slot = 2 * p + (lane >> 5);
            size_t gb = (size_t)w * G_MAT_HALFS / 8 + ((size_t)(kt * 4 + slot)) * 2048 + col0 + (lane & 31);
            glds16(GH + gb * 8, &BH[(w * 128 + p * 64) * 8]);
            glds16(GL + gb * 8, &BL[(w * 128 + p * 64) * 8]);
        }
        __syncthreads();

        f16x8 ah[2], al[2];
#pragma unroll
        for (int mf = 0; mf < 2; ++mf) {
            const int ch = sl * 128 + w * 32 + mf * 16 + lr;
            ah[mf] = *(const f16x8*)&AH[ch * 8];
            al[mf] = *(const f16x8*)&AL[ch * 8];
        }
#pragma unroll
        for (int g = 0; g < 4; ++g) {
#pragma unroll
            for (int nf = 0; nf < 2; ++nf) {
                const int ch = g * 128 + sl * 32 + nf * 16 + lr;
                f16x8 bh = *(const f16x8*)&BH[ch * 8];
                f16x8 bl = *(const f16x8*)&BL[ch * 8];
#pragma unroll
                for (int mf = 0; mf < 2; ++mf) {
                    hh[g][mf][nf] = __builtin_amdgcn_mfma_f32_16x16x32_f16(ah[mf], bh, hh[g][mf][nf], 0, 0, 0);
                    cx[g][mf][nf] = __builtin_amdgcn_mfma_f32_16x16x32_f16(ah[mf], bl, cx[g][mf][nf], 0, 0, 0);
                    cx[g][mf][nf] = __builtin_amdgcn_mfma_f32_16x16x32_f16(al[mf], bh, cx[g][mf][nf], 0, 0, 0);
                }
            }
        }
        __syncthreads();
    }

#pragma unroll
    for (int g = 0; g < 4; ++g)
#pragma unroll
        for (int mf = 0; mf < 2; ++mf)
#pragma unroll
            for (int nf = 0; nf < 2; ++nf)
                hh[g][mf][nf] += cx[g][mf][nf] * (1.0f / 1024.0f);

    // ---------------- Phase B: K=2048 (64 k-steps) ----------------
    f32x4 rhh[2][2] = {};
    f32x4 rcx[2][2] = {};
    for (int kt = 0; kt < 64; ++kt) {
#pragma unroll
        for (int p = 0; p < 2; ++p) {
            size_t ga = ((size_t)(kt * 4 + w)) * 4096 + row0 + p * 64 + lane;
            glds16(SH + ga * 8, &AH[(w * 128 + p * 64) * 8]);
            glds16(SL + ga * 8, &AL[(w * 128 + p * 64) * 8]);
        }
        {
            const int j = w & 1;
            const _Float16* src = (w < 2) ? RH : RL;
            _Float16* dst = (w < 2) ? BH : BL;
            const int slot = 2 * j + (lane >> 5);
            size_t gb = ((size_t)(kt * 4 + slot)) * 2048 + col0 + (lane & 31);
            glds16(src + gb * 8, &dst[(j * 64) * 8]);
        }
        __syncthreads();

        f16x8 ah[2], al[2];
#pragma unroll
        for (int mf = 0; mf < 2; ++mf) {
            const int ch = sl * 128 + w * 32 + mf * 16 + lr;
            ah[mf] = *(const f16x8*)&AH[ch * 8];
            al[mf] = *(const f16x8*)&AL[ch * 8];
        }
#pragma unroll
        for (int nf = 0; nf < 2; ++nf) {
            const int ch = sl * 32 + nf * 16 + lr;
            f16x8 bh = *(const f16x8*)&BH[ch * 8];
            f16x8 bl = *(const f16x8*)&BL[ch * 8];
#pragma unroll
            for (int mf = 0; mf < 2; ++mf) {
                rhh[mf][nf] = __builtin_amdgcn_mfma_f32_16x16x32_f16(ah[mf], bh, rhh[mf][nf], 0, 0, 0);
                rcx[mf][nf] = __builtin_amdgcn_mfma_f32_16x16x32_f16(ah[mf], bl, rcx[mf][nf], 0, 0, 0);
                rcx[mf][nf] = __builtin_amdgcn_mfma_f32_16x16x32_f16(al[mf], bh, rcx[mf][nf], 0, 0, 0);
            }
        }
        __syncthreads();
    }
#pragma unroll
    for (int mf = 0; mf < 2; ++mf)
#pragma unroll
        for (int nf = 0; nf < 2; ++nf)
            rhh[mf][nf] += rcx[mf][nf] * (1.0f / 1024.0f);

    // ---------------- Epilogue ----------------
#pragma unroll
    for (int mf = 0; mf < 2; ++mf) {
#pragma unroll
        for (int nf = 0; nf < 2; ++nf) {
#pragma unroll
            for (int i = 0; i < 4; ++i) {
                const int row = row0 + w * 32 + mf * 16 + (lane >> 4) * 4 + i;
                const int col = col0 + nf * 16 + (lane & 15);
                const float p   = S[(size_t)row * MAXR + col];
                const float vin = hh[0][mf][nf][i];
                const float vi  = hh[1][mf][nf][i];
                const float vf  = hh[2][mf][nf][i];
                const float vo  = hh[3][mf][nf][i];
                const float vr  = rhh[mf][nf][i];
                const float ig = 1.0f / (1.0f + expf(-vi));
                const float fg = 1.0f / (1.0f + expf(-vf));
                const float og = 1.0f / (1.0f + expf(-vo));
                float s = 0.9f * (fg * p) + 0.1f * tanhf(ig * (vin + vr));
                s *= og;
                if (s > 0.5f) s -= 0.5f;
                out[(size_t)row * MAXR + col] = s;
                out[(size_t)row * MAXR + R + col] = 0.0f;
            }
        }
    }
}

// ---------------- fallback: round-5 proven kernel (used only if ws too small) ----------------
__global__ __launch_bounds__(256, 2)
void slnn_mfma_kernel(const float* __restrict__ X, const float* __restrict__ S,
                      const float* __restrict__ Wres, const float* __restrict__ Win,
                      const float* __restrict__ Wg, float* __restrict__ out)
{
    __shared__ _Float16 Ah[BM][BKP];
    __shared__ _Float16 Al[BM][BKP];
    __shared__ _Float16 Bh[4][BN][BKP];
    __shared__ _Float16 Bl[4][BN][BKP];

    const int tid  = threadIdx.x;
    const int w    = tid >> 6;
    const int lane = tid & 63;
    const int row0 = blockIdx.x * BM;
    const int col0 = blockIdx.y * BN;
    const int lrow = lane & 15;
    const int koff = (lane >> 4) * 8;
    const int s_r  = tid >> 3;
    const int s_kq = tid & 7;

    f32x4 hh[4][2][2] = {};
    f32x4 cx[4][2][2] = {};

    for (int k0 = 0; k0 < K1; k0 += BK) {
#pragma unroll
        for (int i = 0; i < 4; ++i) {
            const int row = s_r + 32 * i;
            float4 v = *(const float4*)(X + (size_t)(row0 + row) * K1 + k0 + s_kq * 4);
            f16x4 h, l; split4(v, &h, &l);
            *(f16x4*)&Ah[row][s_kq * 4] = h;
            *(f16x4*)&Al[row][s_kq * 4] = l;
        }
        {
            const int n = s_r;
            f16x4 h, l;
            float4 v0 = *(const float4*)(Win + (size_t)(col0 + n) * K1 + k0 + s_kq * 4);
            split4(v0, &h, &l);
            *(f16x4*)&Bh[0][n][s_kq * 4] = h;
            *(f16x4*)&Bl[0][n][s_kq * 4] = l;
#pragma unroll
            for (int g = 1; g < 4; ++g) {
                float4 v = *(const float4*)(Wg + (size_t)(col0 + n + (g - 1) * R) * K1 + k0 + s_kq * 4);
                split4(v, &h, &l);
                *(f16x4*)&Bh[g][n][s_kq * 4] = h;
                *(f16x4*)&Bl[g][n][s_kq * 4] = l;
            }
        }
        __syncthreads();
        f16x8 ah[2], al[2];
#pragma unroll
        for (int mf = 0; mf < 2; ++mf) {
            const int m = w * 32 + mf * 16 + lrow;
            ah[mf] = *(const f16x8*)&Ah[m][koff];
            al[mf] = *(const f16x8*)&Al[m][koff];
        }
#pragma unroll
        for (int g = 0; g < 4; ++g) {
#pragma unroll
            for (int nf = 0; nf < 2; ++nf) {
                const int n = nf * 16 + lrow;
                f16x8 bh = *(const f16x8*)&Bh[g][n][koff];
                f16x8 bl = *(const f16x8*)&Bl[g][n][koff];
#pragma unroll
                for (int mf = 0; mf < 2; ++mf) {
                    hh[g][mf][nf] = __builtin_amdgcn_mfma_f32_16x16x32_f16(ah[mf], bh, hh[g][mf][nf], 0, 0, 0);
                    cx[g][mf][nf] = __builtin_amdgcn_mfma_f32_16x16x32_f16(ah[mf], bl, cx[g][mf][nf], 0, 0, 0);
                    cx[g][mf][nf] = __builtin_amdgcn_mfma_f32_16x16x32_f16(al[mf], bh, cx[g][mf][nf], 0, 0, 0);
                }
            }
        }
        __syncthreads();
    }
#pragma unroll
    for (int g = 0; g < 4; ++g)
#pragma unroll
        for (int mf = 0; mf < 2; ++mf)
#pragma unroll
            for (int nf = 0; nf < 2; ++nf)
                hh[g][mf][nf] += cx[g][mf][nf] * (1.0f / 1024.0f);

    f32x4 rhh[2][2] = {};
    f32x4 rcx[2][2] = {};
    const int wn  = tid & 31;
    const int wkb = (tid >> 5) * 4;
    for (int k0 = 0; k0 < R; k0 += BK) {
#pragma unroll
        for (int i = 0; i < 4; ++i) {
            const int row = s_r + 32 * i;
            float4 v = *(const float4*)(S + (size_t)(row0 + row) * MAXR + k0 + s_kq * 4);
            f16x4 h, l; split4(v, &h, &l);
            *(f16x4*)&Ah[row][s_kq * 4] = h;
            *(f16x4*)&Al[row][s_kq * 4] = l;
        }
        {
            float4 v;
            v.x = Wres[(size_t)(k0 + wkb + 0) * MAXR + col0 + wn];
            v.y = Wres[(size_t)(k0 + wkb + 1) * MAXR + col0 + wn];
            v.z = Wres[(size_t)(k0 + wkb + 2) * MAXR + col0 + wn];
            v.w = Wres[(size_t)(k0 + wkb + 3) * MAXR + col0 + wn];
            f16x4 h, l; split4(v, &h, &l);
            *(f16x4*)&Bh[0][wn][wkb] = h;
            *(f16x4*)&Bl[0][wn][wkb] = l;
        }
        __syncthreads();
        f16x8 ah[2], al[2];
#pragma unroll
        for (int mf = 0; mf < 2; ++mf) {
            const int m = w * 32 + mf * 16 + lrow;
            ah[mf] = *(const f16x8*)&Ah[m][koff];
            al[mf] = *(const f16x8*)&Al[m][koff];
        }
#pragma unroll
        for (int nf = 0; nf < 2; ++nf) {
            const int n = nf * 16 + lrow;
            f16x8 bh = *(const f16x8*)&Bh[0][n][koff];
            f16x8 bl = *(const f16x8*)&Bl[0][n][koff];
#pragma unroll
            for (int mf = 0; mf < 2; ++mf) {
                rhh[mf][nf] = __builtin_amdgcn_mfma_f32_16x16x32_f16(ah[mf], bh, rhh[mf][nf], 0, 0, 0);
                rcx[mf][nf] = __builtin_amdgcn_mfma_f32_16x16x32_f16(ah[mf], bl, rcx[mf][nf], 0, 0, 0);
                rcx[mf][nf] = __builtin_amdgcn_mfma_f32_16x16x32_f16(al[mf], bh, rcx[mf][nf], 0, 0, 0);
            }
        }
        __syncthreads();
    }
#pragma unroll
    for (int mf = 0; mf < 2; ++mf)
#pragma unroll
        for (int nf = 0; nf < 2; ++nf)
            rhh[mf][nf] += rcx[mf][nf] * (1.0f / 1024.0f);

#pragma unroll
    for (int mf = 0; mf < 2; ++mf) {
#pragma unroll
        for (int nf = 0; nf < 2; ++nf) {
#pragma unroll
            for (int i = 0; i < 4; ++i) {
                const int row = row0 + w * 32 + mf * 16 + (lane >> 4) * 4 + i;
                const int col = col0 + nf * 16 + (lane & 15);
                const float p   = S[(size_t)row * MAXR + col];
                const float vin = hh[0][mf][nf][i];
                const float vi  = hh[1][mf][nf][i];
                const float vf  = hh[2][mf][nf][i];
                const float vo  = hh[3][mf][nf][i];
                const float vr  = rhh[mf][nf][i];
                const float ig = 1.0f / (1.0f + expf(-vi));
                const float fg = 1.0f / (1.0f + expf(-vf));
                const float og = 1.0f / (1.0f + expf(-vo));
                float s = 0.9f * (fg * p) + 0.1f * tanhf(ig * (vin + vr));
                s *= og;
                if (s > 0.5f) s -= 0.5f;
                out[(size_t)row * MAXR + col] = s;
                out[(size_t)row * MAXR + R + col] = 0.0f;
            }
        }
    }
}

extern "C" void kernel_launch(void* const* d_in, const int* in_sizes, int n_in,
                              void* d_out, int out_size, void* d_ws, size_t ws_size,
                              hipStream_t stream) {
    const float* X    = (const float*)d_in[0];
    const float* S    = (const float*)d_in[1];
    const float* Wres = (const float*)d_in[2];
    const float* Win  = (const float*)d_in[3];
    const float* Wg   = (const float*)d_in[4];
    float* out = (float*)d_out;
    dim3 grid(M / BM, R / BN);

    if (ws_size >= WS_NEED) {
        char* ws = (char*)d_ws;
        _Float16* XH = (_Float16*)(ws + WS_XH);
        _Float16* XL = (_Float16*)(ws + WS_XL);
        _Float16* SHp = (_Float16*)(ws + WS_SH);
        _Float16* SLp = (_Float16*)(ws + WS_SL);
        _Float16* GHp = (_Float16*)(ws + WS_GH);
        _Float16* GLp = (_Float16*)(ws + WS_GL);
        _Float16* RHp = (_Float16*)(ws + WS_RH);
        _Float16* RLp = (_Float16*)(ws + WS_RL);

        convert_rowmajor<<<dim3(64, 8),  256, 0, stream>>>(X, K1, XH, XL, 4096);
        convert_rowmajor<<<dim3(64, 16), 256, 0, stream>>>(S, MAXR, SHp, SLp, 4096);
        convert_rowmajor<<<dim3(32, 8),  256, 0, stream>>>(Win, K1, GHp, GLp, 2048);
        for (int g = 0; g < 3; ++g) {
            convert_rowmajor<<<dim3(32, 8), 256, 0, stream>>>(
                Wg + (size_t)g * 2048 * K1, K1,
                GHp + (size_t)(g + 1) * G_MAT_HALFS, GLp + (size_t)(g + 1) * G_MAT_HALFS, 2048);
        }
        convert_colmajor<<<dim3(16, 32), 256, 0, stream>>>(Wres, MAXR, RHp, RLp, 2048);

        slnn_mfma_pre<<<grid, dim3(256), 0, stream>>>(XH, XL, SHp, SLp, GHp, GLp, RHp, RLp, S, out);
    } else {
        slnn_mfma_kernel<<<grid, dim3(256), 0, stream>>>(X, S, Wres, Win, Wg, out);
    }
}